// Round 8
// baseline (256.672 us; speedup 1.0000x reference)
//
#include <hip/hip_runtime.h>

// WaveletParsingLayer: per-row stable stream compaction.
// x3[B,C,L] -> out[B,C,KEEP], dropping elements == FILLER (10.1f), order-preserving.
// x1, x2 are unused by the reference.
//
// R12 == R10 resubmitted a second time (R10, R11 both died on
// GPUAcquisitionTimeout before compile/run; no new evidence).
//
// R10: ledger: R4/R5 value-stage 78-80us | R6 reg-pipeline 90us (spill) |
// R8 index+gather 89us | R9 full-MLP burst + 2rows/block 78us (VGPR=68,
// FETCH clean, WRITE clean -> ILP theory falsified as primary limiter).
// Accounting: per row ~23.4k cyc vs 11.2k BW floor; VALU ~4k, LDS ~1k,
// latency ~1k -> remaining ~6k = barrier-convoy idle (load|barrier|scatter|
// barrier|copyout phase-lock across resident blocks, HBM duty ~40%).
// Fix: ONE WAVE PER ROW, ZERO BARRIERS. Stream 256-elem chunks:
// ballot -> v_mbcnt lane-prefix -> SGPR running offset (s_bcnt1 totals) ->
// scatter into 8KB LDS ring -> flush 1KB coalesced (ds_read_b128 +
// global_store_dwordx4) whenever >=256 floats pending. 8-deep float4
// prefetch/wave (static indexing) keeps 8KB/wave in flight: 8 waves/CU =
// 64KB >> 9.2KB needed to cover ~900cy HBM latency at 10.25 B/cyc/CU.
// Load/VALU/LDS/store interleave at 256-elem grain -> no burst-idle-burst.
// Ring safety: backlog<=255 + chunk<=256 = 511 in-flight < 2048 capacity.
// Guard metric: WRITE_SIZE must stay exactly 98304 KB (no spill/scratch).

#define FILLER_VAL 10.1f
constexpr int L_LEN    = 16384;
constexpr int KEEP_LEN = 12288;
constexpr int WAVE     = 64;
constexpr int CHUNK    = WAVE * 4;        // 256 elements per chunk
constexpr int CPR      = L_LEN / CHUNK;   // 64 chunks per row
constexpr int PF       = 8;               // prefetch depth (chunks in flight)
constexpr int RING     = 2048;            // ring capacity (floats), 8 KB
constexpr int RM       = RING - 1;
constexpr int FLUSH_Q  = 256;             // flush quantum (floats) = 1 KB

__device__ __forceinline__ int lane_prefix(unsigned long long m)
{
    // popcount(m & ((1<<lane)-1)) in 2 VALU ops, no LDS round-trips.
    return __builtin_amdgcn_mbcnt_hi((unsigned)(m >> 32),
           __builtin_amdgcn_mbcnt_lo((unsigned)m, 0u));
}

__global__ __launch_bounds__(WAVE, 4) void compact_rows_kernel(
    const float* __restrict__ x3, float* __restrict__ out)
{
    const int row  = blockIdx.x;
    const int lane = threadIdx.x;              // 0..63 (one wave per block)
    const float* __restrict__ in = x3 + (size_t)row * L_LEN;
    float* __restrict__ o = out + (size_t)row * KEEP_LEN;

    __shared__ float ring[RING];               // 8 KB survivor ring

    // ---- Prologue: fill the 8-deep prefetch pipeline.
    float4 buf[PF];
    #pragma unroll
    for (int i = 0; i < PF; ++i)
        buf[i] = *reinterpret_cast<const float4*>(in + i * CHUNK + lane * 4);

    int rowoff  = 0;   // wave-uniform (SGPR): survivors emitted so far
    int flushed = 0;   // wave-uniform (SGPR): floats written to global

    #pragma unroll 1
    for (int g = 0; g < CPR / PF; ++g) {
        #pragma unroll
        for (int s = 0; s < PF; ++s) {         // s compile-time -> buf[] static
            const int c = g * PF + s;
            const float4 v = buf[s];
            // Issue the replacement load immediately: ~8 chunks of work
            // (~800cy) before this slot is consumed again.
            if (c + PF < CPR)
                buf[s] = *reinterpret_cast<const float4*>(
                    in + (c + PF) * CHUNK + lane * 4);

            // Survivor masks (element order within chunk: lane*4 + j).
            const bool kx = (v.x != FILLER_VAL);
            const bool ky = (v.y != FILLER_VAL);
            const bool kz = (v.z != FILLER_VAL);
            const bool kw = (v.w != FILLER_VAL);
            const unsigned long long m0 = __ballot(kx);
            const unsigned long long m1 = __ballot(ky);
            const unsigned long long m2 = __ballot(kz);
            const unsigned long long m3 = __ballot(kw);

            // Exclusive prefix: all elements of lower lanes + own prior elems.
            const int before = lane_prefix(m0) + lane_prefix(m1)
                             + lane_prefix(m2) + lane_prefix(m3);
            const int p0 = rowoff + before;
            const int p1 = p0 + (int)kx;
            const int p2 = p1 + (int)ky;
            const int p3 = p2 + (int)kz;
            if (kx) ring[p0 & RM] = v.x;
            if (ky) ring[p1 & RM] = v.y;
            if (kz) ring[p2 & RM] = v.z;
            if (kw) ring[p3 & RM] = v.w;

            // Wave totals on the scalar pipe; rowoff stays in SGPR.
            rowoff += __popcll(m0) + __popcll(m1)
                    + __popcll(m2) + __popcll(m3);

            // Flush full 1KB quanta: coalesced b128 read + dwordx4 store.
            while (rowoff - flushed >= FLUSH_Q) {     // uniform branch
                const int rbase = (flushed & RM) + lane * 4;  // 16B-aligned
                const float4 t = *reinterpret_cast<const float4*>(&ring[rbase]);
                if (flushed < KEEP_LEN)
                    *reinterpret_cast<float4*>(&o[flushed + lane * 4]) = t;
                flushed += FLUSH_Q;
            }
        }
    }

    // ---- Tail: (rowoff - flushed) in [0,255]; 0 in practice (12288 % 256 == 0).
    const int rem = rowoff - flushed;
    #pragma unroll
    for (int j = 0; j < 4; ++j) {
        const int i = lane * 4 + j;
        if (i < rem && flushed + i < KEEP_LEN)
            o[flushed + i] = ring[(flushed + i) & RM];
    }
}

extern "C" void kernel_launch(void* const* d_in, const int* in_sizes, int n_in,
                              void* d_out, int out_size, void* d_ws, size_t ws_size,
                              hipStream_t stream)
{
    // in order: x1 [B,C,4096] f32 (unused), x2 [B,C,4096] f32 (unused),
    //           x3 [B,C,L] f32, keep_len (scalar int, value 12288)
    const float* x3 = (const float*)d_in[2];
    float* out = (float*)d_out;

    const int rows = in_sizes[2] / L_LEN;  // B*C = 2048

    compact_rows_kernel<<<rows, WAVE, 0, stream>>>(x3, out);
}